// Round 6
// baseline (140.581 us; speedup 1.0000x reference)
//
#include <hip/hip_runtime.h>
#include <hip/hip_fp16.h>

// Triangulated-bilinear interp, B=8, N=262144 (512x512), T=2M targets.
// Round-6: 8 targets/thread -> 24 rec-gather loads in flight per thread
// (2x MLP vs R5's 12) to test latency-bound vs fabric-ceiling hypothesis.
// Keeps: 64B/cell fp16 record (1 line/target), NT tgt loads + out stores.

typedef float  f32x4 __attribute__((ext_vector_type(4)));
typedef unsigned int u32x4 __attribute__((ext_vector_type(4)));

union HalfPack8 { __half h[8]; u32x4 u; };

__global__ __launch_bounds__(256) void build_records_kernel(
    const float* __restrict__ x,   // (B=8, N)
    u32x4* __restrict__ rec,       // (ncells, 4) 16B chunks = 64B per cell
    const int* __restrict__ nx_p,
    int N)
{
    const int nx = *nx_p;
    const int ny = N / nx;
    const int ncx = nx - 1;
    const int ncells = ncx * (ny - 1);
    int c = blockIdx.x * blockDim.x + threadIdx.x;
    if (c >= ncells) return;
    int i = c % ncx;
    int j = c / ncx;
    long base = (long)j * nx + i;

    HalfPack8 p00, p10, p01, p11;
    #pragma unroll
    for (int b = 0; b < 8; ++b) {
        const float* xb = x + (long)b * N;
        p00.h[b] = __float2half(xb[base]);
        p10.h[b] = __float2half(xb[base + 1]);
        p01.h[b] = __float2half(xb[base + nx]);
        p11.h[b] = __float2half(xb[base + nx + 1]);
    }
    u32x4* dst = rec + (long)c * 4;
    dst[0] = p00.u;
    dst[1] = p10.u;
    dst[2] = p01.u;
    dst[3] = p11.u;
}

__device__ __forceinline__ void half8_to_float8(u32x4 u, float* f) {
    union { u32x4 v; __half2 h2[4]; } cv;
    cv.v = u;
    float2 a = __half22float2(cv.h2[0]); f[0] = a.x; f[1] = a.y;
    float2 b = __half22float2(cv.h2[1]); f[2] = b.x; f[3] = b.y;
    float2 c = __half22float2(cv.h2[2]); f[4] = c.x; f[5] = c.y;
    float2 d = __half22float2(cv.h2[3]); f[6] = d.x; f[7] = d.y;
}

__global__ __launch_bounds__(256, 2) void interp_rec_kernel(
    const u32x4* __restrict__ rec,   // (ncells, 4)
    const float* __restrict__ src_x,
    const float* __restrict__ src_y,
    const float* __restrict__ tgt_x,
    const float* __restrict__ tgt_y,
    const int* __restrict__ nx_p,
    float* __restrict__ out,
    int T, int N)
{
    const int nx = *nx_p;
    const int ny = N / nx;
    const int ncx = nx - 1;
    const float x0 = src_x[0];
    const float x1 = src_x[nx - 1];
    const float y0 = src_y[0];
    const float y1 = src_y[N - 1];
    const float inv_dx = (float)(nx - 1) / (x1 - x0);
    const float inv_dy = (float)(ny - 1) / (y1 - y0);

    const int t0 = (blockIdx.x * blockDim.x + threadIdx.x) * 8;
    if (t0 >= T) return;

    if (t0 + 8 <= T) {
        // Streaming reads: keep them out of L2 (rec wants the capacity).
        f32x4 txl = __builtin_nontemporal_load(
            reinterpret_cast<const f32x4*>(tgt_x + t0));
        f32x4 txh = __builtin_nontemporal_load(
            reinterpret_cast<const f32x4*>(tgt_x + t0 + 4));
        f32x4 tyl = __builtin_nontemporal_load(
            reinterpret_cast<const f32x4*>(tgt_y + t0));
        f32x4 tyh = __builtin_nontemporal_load(
            reinterpret_cast<const f32x4*>(tgt_y + t0 + 4));

        // ---- Phase 1: all addresses + weights (no memory waits) ----
        const u32x4* p0[8];
        const u32x4* p1[8];
        const u32x4* p2[8];
        float w0a[8], w1a[8], w2a[8];
        #pragma unroll
        for (int k = 0; k < 8; ++k) {
            float tx = (k < 4) ? txl[k] : txh[k - 4];
            float ty = (k < 4) ? tyl[k] : tyh[k - 4];
            float fx = (tx - x0) * inv_dx;
            float fy = (ty - y0) * inv_dy;
            float ix = fminf(fmaxf(floorf(fx), 0.0f), (float)(nx - 2));
            float iy = fminf(fmaxf(floorf(fy), 0.0f), (float)(ny - 2));
            float u = fx - ix;
            float v = fy - iy;
            bool lower = (u + v) <= 1.0f;
            int c = (int)iy * ncx + (int)ix;
            const u32x4* r = rec + (long)c * 4;
            p0[k] = r + (lower ? 0 : 3);
            p1[k] = r + 1;
            p2[k] = r + 2;
            w0a[k] = lower ? (1.0f - u - v) : (u + v - 1.0f);
            w1a[k] = lower ? u : (1.0f - v);
            w2a[k] = lower ? v : (1.0f - u);
        }

        // ---- Phase 2: issue ALL 24 loads before any use ----
        u32x4 r0[8], r1[8], r2[8];
        #pragma unroll
        for (int k = 0; k < 8; ++k) { r0[k] = *p0[k]; }
        #pragma unroll
        for (int k = 0; k < 8; ++k) { r1[k] = *p1[k]; }
        #pragma unroll
        for (int k = 0; k < 8; ++k) { r2[k] = *p2[k]; }

        // ---- Phase 3: convert + FMA ----
        float res[8][8];   // [k][b]
        #pragma unroll
        for (int k = 0; k < 8; ++k) {
            float f0[8], f1[8], f2[8];
            half8_to_float8(r0[k], f0);
            half8_to_float8(r1[k], f1);
            half8_to_float8(r2[k], f2);
            #pragma unroll
            for (int b = 0; b < 8; ++b)
                res[k][b] = f0[b] * w0a[k] + f1[b] * w1a[k] + f2[b] * w2a[k];
        }

        // ---- Phase 4: non-temporal coalesced stores (two x4 per batch) ----
        #pragma unroll
        for (int b = 0; b < 8; ++b) {
            f32x4 lo = { res[0][b], res[1][b], res[2][b], res[3][b] };
            f32x4 hi = { res[4][b], res[5][b], res[6][b], res[7][b] };
            float* dst = out + (long)b * T + t0;
            __builtin_nontemporal_store(lo, reinterpret_cast<f32x4*>(dst));
            __builtin_nontemporal_store(hi, reinterpret_cast<f32x4*>(dst + 4));
        }
    } else {
        for (int t = t0; t < T; ++t) {
            float fx = (tgt_x[t] - x0) * inv_dx;
            float fy = (tgt_y[t] - y0) * inv_dy;
            float ix = fminf(fmaxf(floorf(fx), 0.0f), (float)(nx - 2));
            float iy = fminf(fmaxf(floorf(fy), 0.0f), (float)(ny - 2));
            float u = fx - ix;
            float v = fy - iy;
            bool lower = (u + v) <= 1.0f;
            int c = (int)iy * ncx + (int)ix;
            const u32x4* r = rec + (long)c * 4;
            u32x4 q0 = r[lower ? 0 : 3], q1 = r[1], q2 = r[2];
            float w0 = lower ? (1.0f - u - v) : (u + v - 1.0f);
            float w1 = lower ? u : (1.0f - v);
            float w2 = lower ? v : (1.0f - u);
            float f0[8], f1[8], f2[8];
            half8_to_float8(q0, f0);
            half8_to_float8(q1, f1);
            half8_to_float8(q2, f2);
            for (int b = 0; b < 8; ++b)
                out[(long)b * T + t] = f0[b] * w0 + f1[b] * w1 + f2[b] * w2;
        }
    }
}

// Fallback: direct fp32 path, used only if ws too small.
__global__ __launch_bounds__(256) void interp_fallback_kernel(
    const float* __restrict__ x,
    const float* __restrict__ src_x,
    const float* __restrict__ src_y,
    const float* __restrict__ tgt_x,
    const float* __restrict__ tgt_y,
    const int* __restrict__ nx_p,
    float* __restrict__ out,
    int T, int N, int B)
{
    const int nx = *nx_p;
    const int ny = N / nx;
    const float x0 = src_x[0];
    const float x1 = src_x[nx - 1];
    const float y0 = src_y[0];
    const float y1 = src_y[N - 1];
    const float dx = (x1 - x0) / (float)(nx - 1);
    const float dy = (y1 - y0) / (float)(ny - 1);

    const int t = blockIdx.x * blockDim.x + threadIdx.x;
    if (t >= T) return;
    float fx = (tgt_x[t] - x0) / dx;
    float fy = (tgt_y[t] - y0) / dy;
    float ix = fminf(fmaxf(floorf(fx), 0.0f), (float)(nx - 2));
    float iy = fminf(fmaxf(floorf(fy), 0.0f), (float)(ny - 2));
    float u = fx - ix;
    float v = fy - iy;
    int base = (int)iy * nx + (int)ix;
    bool lower = (u + v) <= 1.0f;
    int   i0 = lower ? base : (base + nx + 1);
    int   i1 = base + 1;
    int   i2 = base + nx;
    float w0 = lower ? (1.0f - u - v) : (u + v - 1.0f);
    float w1 = lower ? u : (1.0f - v);
    float w2 = lower ? v : (1.0f - u);
    for (int b = 0; b < B; ++b) {
        const float* xb = x + (long)b * N;
        out[(long)b * T + t] = xb[i0] * w0 + xb[i1] * w1 + xb[i2] * w2;
    }
}

extern "C" void kernel_launch(void* const* d_in, const int* in_sizes, int n_in,
                              void* d_out, int out_size, void* d_ws, size_t ws_size,
                              hipStream_t stream) {
    const float* x     = (const float*)d_in[0];
    const float* src_x = (const float*)d_in[1];
    const float* src_y = (const float*)d_in[2];
    const float* tgt_x = (const float*)d_in[3];
    const float* tgt_y = (const float*)d_in[4];
    const int*   nx_p  = (const int*)d_in[5];
    float* out = (float*)d_out;

    const int N = in_sizes[1];            // nx*ny = 262144
    const int T = in_sizes[3];            // 2,000,000
    const int B = in_sizes[0] / N;        // 8

    const size_t rec_bytes = (size_t)N * 64;

    if (B == 8 && ws_size >= rec_bytes) {
        u32x4* rec = (u32x4*)d_ws;
        {
            const int block = 256;
            const int grid = (N + block - 1) / block;
            build_records_kernel<<<grid, block, 0, stream>>>(x, rec, nx_p, N);
        }
        {
            const int threads_needed = (T + 7) / 8;
            const int block = 256;
            const int grid = (threads_needed + block - 1) / block;
            interp_rec_kernel<<<grid, block, 0, stream>>>(
                rec, src_x, src_y, tgt_x, tgt_y, nx_p, out, T, N);
        }
    } else {
        const int block = 256;
        const int grid = (T + block - 1) / block;
        interp_fallback_kernel<<<grid, block, 0, stream>>>(
            x, src_x, src_y, tgt_x, tgt_y, nx_p, out, T, N, B);
    }
}